// Round 2
// baseline (83.306 us; speedup 1.0000x reference)
//
#include <hip/hip_runtime.h>

#define NV   6890
#define NF   13776
#define NFP  13888            // 64 + 27*512; multiple of 64; sentinel-padded
#define KMAX 8
#define EPS  1e-8f
#define CBLK 1024             // coll blocks: 4 waves each -> 4096 waves

// ---------------------------------------------------------------------------
// Per-face precompute. Packed layout:
//   lo4[f] = {lox, loy, loz, asfloat(f0)}
//   hi4[f] = {hix, hiy, hiz, asfloat(f1)}
//   f2[f]  = third vertex id
//   tri[3f..3f+2] = 12 floats: ax ay az bx | by bz cx cy | cz 0 0 0
// Entries [NF, NFP) are +/-INF sentinels that can never overlap anything.
// Thread 0 also zeroes the last-block ticket used by coll_kernel.
__global__ __launch_bounds__(256) void prep_kernel(
    const float* __restrict__ verts,   // [NV,3]
    const int*   __restrict__ faces,   // [NF*3]
    float4* __restrict__ tri,          // [NFP*3]
    float4* __restrict__ lo4, float4* __restrict__ hi4,
    int* __restrict__ f2,
    int* __restrict__ ticket)
{
    int f = blockIdx.x * blockDim.x + threadIdx.x;
    if (f == 0) *ticket = 0;
    if (f >= NFP) return;
    if (f >= NF) {
        lo4[f] = make_float4(INFINITY, INFINITY, INFINITY, __int_as_float(-1));
        hi4[f] = make_float4(-INFINITY, -INFINITY, -INFINITY, __int_as_float(-1));
        f2[f]  = -1;
        return;
    }
    int ia = faces[3 * f + 0], ib = faces[3 * f + 1], ic = faces[3 * f + 2];
    float ax = verts[3 * ia + 0], ay = verts[3 * ia + 1], az = verts[3 * ia + 2];
    float bx = verts[3 * ib + 0], by = verts[3 * ib + 1], bz = verts[3 * ib + 2];
    float cx = verts[3 * ic + 0], cy = verts[3 * ic + 1], cz = verts[3 * ic + 2];
    tri[3 * f + 0] = make_float4(ax, ay, az, bx);
    tri[3 * f + 1] = make_float4(by, bz, cx, cy);
    tri[3 * f + 2] = make_float4(cz, 0.f, 0.f, 0.f);
    lo4[f] = make_float4(fminf(ax, fminf(bx, cx)),
                         fminf(ay, fminf(by, cy)),
                         fminf(az, fminf(bz, cz)), __int_as_float(ia));
    hi4[f] = make_float4(fmaxf(ax, fmaxf(bx, cx)),
                         fmaxf(ay, fmaxf(by, cy)),
                         fmaxf(az, fmaxf(bz, cz)), __int_as_float(ib));
    f2[f] = ic;
}

// ---------------------------------------------------------------------------
// Per-vertex conical penalty term: field of triangle s[9] at point (px,py,pz).
// SIGMA=0.5, POINT2PLANE=False, PENALIZE_OUTSIDE=True.
__device__ __forceinline__ float cone_pen_v(const float* s,
                                            float px, float py, float pz) {
    float e0x = s[3] - s[0], e0y = s[4] - s[1], e0z = s[5] - s[2];
    float e1x = s[6] - s[0], e1y = s[7] - s[1], e1z = s[8] - s[2];
    float nx = e0y * e1z - e0z * e1y;
    float ny = e0z * e1x - e0x * e1z;
    float nz = e0x * e1y - e0y * e1x;
    float inv = 1.0f / (sqrtf(nx * nx + ny * ny + nz * nz) + EPS);
    nx *= inv; ny *= inv; nz *= inv;
    const float third = 1.0f / 3.0f;
    float cx = (s[0] + s[3] + s[6]) * third;
    float cy = (s[1] + s[4] + s[7]) * third;
    float cz = (s[2] + s[5] + s[8]) * third;
    float ux = px - cx, uy = py - cy, uz = pz - cz;
    float h = ux * nx + uy * ny + uz * nz;
    float rx = ux - h * nx, ry = uy - h * ny, rz = uz - h * nz;
    float r = sqrtf(rx * rx + ry * ry + rz * rz);
    float radial = fmaxf(0.0f, 1.0f - 2.0f * r);         // 1 - r/SIGMA
    // relu(-h) + relu(h)*exp(-h/SIGMA) == h<0 ? -h : h*expf(-2h)
    float depth = (h < 0.0f) ? -h : h * expf(-2.0f * h);
    float phi = radial * depth;
    return phi * phi;                                     // POINT2PLANE=False
}

// ---------------------------------------------------------------------------
// Grid-stride wave per receiver. Fast path: chunk 0 (candidates 0..63, cached
// in registers per wave). Rare slow path: batched 512-candidate scan.
// Ballot bits in lane order = ascending j -> stable top_k reproduced exactly.
// Final reduction is fused: each block writes its partial, then the LAST
// block (device-scope fenced ticket) replays the exact old reduce_kernel
// summation order -> bit-identical output, one fewer dispatch.
__global__ __launch_bounds__(256) void coll_kernel(
    const float4* __restrict__ tri,
    const float4* __restrict__ lo4, const float4* __restrict__ hi4,
    const int* __restrict__ f2,
    float* __restrict__ partial,
    int* __restrict__ ticket,
    float* __restrict__ out)
{
    const int lane = threadIdx.x & 63;
    const int wid  = threadIdx.x >> 6;
    const int gw   = (blockIdx.x * blockDim.x + threadIdx.x) >> 6;
    const int nw   = (gridDim.x * blockDim.x) >> 6;

    // Chunk-0 candidate data is wave-invariant: load once.
    const float4 c0lo = lo4[lane];
    const float4 c0hi = hi4[lane];
    const int    c0f2 = f2[lane];
    const int    c0a  = __float_as_int(c0lo.w);
    const int    c0b  = __float_as_int(c0hi.w);

    float acc = 0.0f;

    for (int i = gw; i < NF; i += nw) {
        float4 rlo = lo4[i], rhi = hi4[i];
        int fa0 = __float_as_int(rlo.w);
        int fa1 = __float_as_int(rhi.w);
        int fa2 = f2[i];

        int nc = 0;
        int hj = -1;                                     // this lane's hit slot

        // ---- fast path: chunk 0 from registers ----
        {
            bool ov = (rlo.x <= c0hi.x) & (c0lo.x <= rhi.x)
                    & (rlo.y <= c0hi.y) & (c0lo.y <= rhi.y)
                    & (rlo.z <= c0hi.z) & (c0lo.z <= rhi.z);
            bool share = (c0a  == fa0) | (c0a  == fa1) | (c0a  == fa2)
                       | (c0b  == fa0) | (c0b  == fa1) | (c0b  == fa2)
                       | (c0f2 == fa0) | (c0f2 == fa1) | (c0f2 == fa2);
            bool valid = ov & !share;
            unsigned long long mask = __ballot(valid);
            int cnt = __popcll(mask);
            nc = min(cnt, KMAX);
            if (lane < nc) {
                unsigned long long m = mask;
                for (int q = 0; q < lane; ++q) m &= (m - 1);
                hj = __builtin_ctzll(m);
            }
        }

        // ---- rare slow path: batched pipelined scan of candidates 64..NFP ----
        if (nc < KMAX) {
            for (int base = 64; base < NFP && nc < KMAX; base += 512) {
                float4 blo[8], bhi[8];
                int    bf2[8];
#pragma unroll
                for (int u = 0; u < 8; ++u) {
                    int j = base + (u << 6) + lane;
                    blo[u] = lo4[j];
                    bhi[u] = hi4[j];
                    bf2[u] = f2[j];
                }
#pragma unroll
                for (int u = 0; u < 8; ++u) {
                    bool ov = (rlo.x <= bhi[u].x) & (blo[u].x <= rhi.x)
                            & (rlo.y <= bhi[u].y) & (blo[u].y <= rhi.y)
                            & (rlo.z <= bhi[u].z) & (blo[u].z <= rhi.z);
                    int fb0 = __float_as_int(blo[u].w);
                    int fb1 = __float_as_int(bhi[u].w);
                    bool share = (fb0    == fa0) | (fb0    == fa1) | (fb0    == fa2)
                               | (fb1    == fa0) | (fb1    == fa1) | (fb1    == fa2)
                               | (bf2[u] == fa0) | (bf2[u] == fa1) | (bf2[u] == fa2);
                    bool valid = ov & !share;
                    unsigned long long mask = __ballot(valid);
                    int cnt  = __popcll(mask);
                    int take = min(cnt, KMAX - nc);
                    if (take > 0 && lane >= nc && lane < nc + take) {
                        int t = lane - nc;               // t-th set bit
                        unsigned long long m = mask;
                        for (int q = 0; q < t; ++q) m &= (m - 1);
                        hj = base + (u << 6) + __builtin_ctzll(m);
                    }
                    nc += take;
                }
            }
        }

        // ---- penalty phase: lane = k*8 + t, t<6 live ----
        int k = lane >> 3;                               // pair index 0..7
        int t = lane & 7;                                // term index
        int hjk = __shfl(hj, k);
        float p = 0.0f;
        if (t < 6 && k < nc) {
            int d = (t >= 3) ? 1 : 0;                    // 0: recv field @ intr verts
            int v = t - 3 * d;
            int si = d ? hjk : i;                        // field source tri
            int qi = d ? i : hjk;                        // query tri
            float4 s0 = tri[3 * si + 0];
            float4 s1 = tri[3 * si + 1];
            float4 s2 = tri[3 * si + 2];
            float s[9] = { s0.x, s0.y, s0.z, s0.w, s1.x, s1.y, s1.z, s1.w, s2.x };
            const float* qp = (const float*)(tri + 3 * qi);
            p = cone_pen_v(s, qp[3 * v + 0], qp[3 * v + 1], qp[3 * v + 2]);
        }
        acc += p;
    }

    // 64-lane butterfly, then block reduce, then one partial store per block.
#pragma unroll
    for (int off = 32; off > 0; off >>= 1) acc += __shfl_xor(acc, off);
    __shared__ float wsum[4];
    __shared__ int isLast;
    if (lane == 0) wsum[wid] = acc;
    __syncthreads();
    if (threadIdx.x == 0) {
        partial[blockIdx.x] = wsum[0] + wsum[1] + wsum[2] + wsum[3];
        __threadfence();                                 // release partial store
        int t = atomicAdd(ticket, 1);                    // device-scope
        isLast = (t == (int)gridDim.x - 1);
    }
    __syncthreads();

    // Last block replays the old reduce_kernel EXACTLY (same summation order
    // -> bit-identical result, deterministic regardless of which block is last).
    if (isLast) {
        __threadfence();                                 // acquire partials
        float a = 0.0f;
        for (int idx = threadIdx.x; idx < CBLK; idx += 256) a += partial[idx];
#pragma unroll
        for (int off = 32; off > 0; off >>= 1) a += __shfl_xor(a, off);
        if (lane == 0) wsum[wid] = a;
        __syncthreads();
        if (threadIdx.x == 0) out[0] = wsum[0] + wsum[1] + wsum[2] + wsum[3];
    }
}

// ---------------------------------------------------------------------------
extern "C" void kernel_launch(void* const* d_in, const int* in_sizes, int n_in,
                              void* d_out, int out_size, void* d_ws, size_t ws_size,
                              hipStream_t stream) {
    const float* verts = (const float*)d_in[0];   // [1,NV,3] fp32
    const int*   faces = (const int*)d_in[1];     // [NF*3] int32
    float* out = (float*)d_out;                   // scalar fp32

    float4* tri = (float4*)d_ws;                  // NFP*3 float4
    float4* lo4 = tri + NFP * 3;                  // NFP float4
    float4* hi4 = lo4 + NFP;                      // NFP float4
    int*    f2  = (int*)(hi4 + NFP);              // NFP int
    float*  partial = (float*)(f2 + NFP);         // CBLK floats
    int*    ticket  = (int*)(partial + CBLK);     // 1 int

    prep_kernel<<<(NFP + 255) / 256, 256, 0, stream>>>(verts, faces, tri, lo4, hi4, f2, ticket);
    coll_kernel<<<CBLK, 256, 0, stream>>>(tri, lo4, hi4, f2, partial, ticket, out);
}

// Round 3
// 66.660 us; speedup vs baseline: 1.2497x; 1.2497x over previous
//
#include <hip/hip_runtime.h>

#define NV   6890
#define NF   13776
#define KMAX 8
#define EPS  1e-8f
#define CBLK 1024             // coll blocks: 4 waves each -> 4096 waves

// ---------------------------------------------------------------------------
// On-the-fly per-face data (replaces the old prep_kernel; verts/faces are
// L1/L2-resident at 82KB+165KB, so gathers are cache hits and one dispatch
// plus its graph-node gap is saved).
// AABB arithmetic is replicated EXACTLY from the old prep (same fminf/fmaxf
// order) so all comparisons are bit-identical.
__device__ __forceinline__ void face_aabb(const float* __restrict__ verts,
                                          const int*   __restrict__ faces,
                                          int f,
                                          float& lx, float& ly, float& lz,
                                          float& hx, float& hy, float& hz,
                                          int& i0, int& i1, int& i2)
{
    i0 = faces[3 * f + 0]; i1 = faces[3 * f + 1]; i2 = faces[3 * f + 2];
    float ax = verts[3 * i0 + 0], ay = verts[3 * i0 + 1], az = verts[3 * i0 + 2];
    float bx = verts[3 * i1 + 0], by = verts[3 * i1 + 1], bz = verts[3 * i1 + 2];
    float cx = verts[3 * i2 + 0], cy = verts[3 * i2 + 1], cz = verts[3 * i2 + 2];
    lx = fminf(ax, fminf(bx, cx));
    ly = fminf(ay, fminf(by, cy));
    lz = fminf(az, fminf(bz, cz));
    hx = fmaxf(ax, fmaxf(bx, cx));
    hy = fmaxf(ay, fmaxf(by, cy));
    hz = fmaxf(az, fmaxf(bz, cz));
}

// ---------------------------------------------------------------------------
// Per-vertex conical penalty term: field of triangle s[9] at point (px,py,pz).
// SIGMA=0.5, POINT2PLANE=False, PENALIZE_OUTSIDE=True. Unchanged arithmetic.
__device__ __forceinline__ float cone_pen_v(const float* s,
                                            float px, float py, float pz) {
    float e0x = s[3] - s[0], e0y = s[4] - s[1], e0z = s[5] - s[2];
    float e1x = s[6] - s[0], e1y = s[7] - s[1], e1z = s[8] - s[2];
    float nx = e0y * e1z - e0z * e1y;
    float ny = e0z * e1x - e0x * e1z;
    float nz = e0x * e1y - e0y * e1x;
    float inv = 1.0f / (sqrtf(nx * nx + ny * ny + nz * nz) + EPS);
    nx *= inv; ny *= inv; nz *= inv;
    const float third = 1.0f / 3.0f;
    float cx = (s[0] + s[3] + s[6]) * third;
    float cy = (s[1] + s[4] + s[7]) * third;
    float cz = (s[2] + s[5] + s[8]) * third;
    float ux = px - cx, uy = py - cy, uz = pz - cz;
    float h = ux * nx + uy * ny + uz * nz;
    float rx = ux - h * nx, ry = uy - h * ny, rz = uz - h * nz;
    float r = sqrtf(rx * rx + ry * ry + rz * rz);
    float radial = fmaxf(0.0f, 1.0f - 2.0f * r);         // 1 - r/SIGMA
    // relu(-h) + relu(h)*exp(-h/SIGMA) == h<0 ? -h : h*exp(-2h)
    float depth = (h < 0.0f) ? -h : h * expf(-2.0f * h);
    float phi = radial * depth;
    return phi * phi;                                     // POINT2PLANE=False
}

// ---------------------------------------------------------------------------
// Grid-stride wave per receiver, prep fused in (no materialized AABB/tri
// arrays, no prep dispatch). Fast path: chunk 0 (candidates 0..63, AABBs
// computed once per wave and held in registers). Rare slow path: serial
// chunk scan with j<NF masking (R1 proved the slow path is not on the
// critical path, so simple is fine). Ballot bits in lane order = ascending j
// -> stable top_k reproduced exactly. NO device-scope fences (R2: +16us).
__global__ __launch_bounds__(256) void coll_kernel(
    const float* __restrict__ verts,
    const int*   __restrict__ faces,
    float* __restrict__ partial)
{
    const int lane = threadIdx.x & 63;
    const int wid  = threadIdx.x >> 6;
    const int gw   = (blockIdx.x * blockDim.x + threadIdx.x) >> 6;
    const int nw   = (gridDim.x * blockDim.x) >> 6;

    // Chunk-0 candidate data is wave-invariant: compute once, keep in regs.
    float c0lx, c0ly, c0lz, c0hx, c0hy, c0hz;
    int c0a, c0b, c0c;
    face_aabb(verts, faces, lane, c0lx, c0ly, c0lz, c0hx, c0hy, c0hz,
              c0a, c0b, c0c);

    float acc = 0.0f;

    for (int i = gw; i < NF; i += nw) {
        // Receiver AABB + vertex ids (wave-uniform gathers, cache hits).
        float rlx, rly, rlz, rhx, rhy, rhz;
        int fa0, fa1, fa2;
        face_aabb(verts, faces, i, rlx, rly, rlz, rhx, rhy, rhz,
                  fa0, fa1, fa2);

        int nc = 0;
        int hj = -1;                                     // this lane's hit slot

        // ---- fast path: chunk 0 from registers ----
        {
            bool ov = (rlx <= c0hx) & (c0lx <= rhx)
                    & (rly <= c0hy) & (c0ly <= rhy)
                    & (rlz <= c0hz) & (c0lz <= rhz);
            bool share = (c0a == fa0) | (c0a == fa1) | (c0a == fa2)
                       | (c0b == fa0) | (c0b == fa1) | (c0b == fa2)
                       | (c0c == fa0) | (c0c == fa1) | (c0c == fa2);
            bool valid = ov & !share;
            unsigned long long mask = __ballot(valid);
            int cnt = __popcll(mask);
            nc = min(cnt, KMAX);
            if (lane < nc) {
                unsigned long long m = mask;
                for (int q = 0; q < lane; ++q) m &= (m - 1);
                hj = __builtin_ctzll(m);
            }
        }

        // ---- rare slow path: scan candidates 64..NF ----
        if (nc < KMAX) {
            for (int base = 64; base < NF && nc < KMAX; base += 64) {
                int j = base + lane;
                int jc = min(j, NF - 1);                 // clamp, mask below
                float jlx, jly, jlz, jhx, jhy, jhz;
                int fb0, fb1, fb2;
                face_aabb(verts, faces, jc, jlx, jly, jlz, jhx, jhy, jhz,
                          fb0, fb1, fb2);
                bool ov = (rlx <= jhx) & (jlx <= rhx)
                        & (rly <= jhy) & (jly <= rhy)
                        & (rlz <= jhz) & (jlz <= rhz);
                bool share = (fb0 == fa0) | (fb0 == fa1) | (fb0 == fa2)
                           | (fb1 == fa0) | (fb1 == fa1) | (fb1 == fa2)
                           | (fb2 == fa0) | (fb2 == fa1) | (fb2 == fa2);
                bool valid = ov & !share & (j < NF);
                unsigned long long mask = __ballot(valid);
                int cnt  = __popcll(mask);
                int take = min(cnt, KMAX - nc);
                if (take > 0 && lane >= nc && lane < nc + take) {
                    int t = lane - nc;                   // t-th set bit
                    unsigned long long m = mask;
                    for (int q = 0; q < t; ++q) m &= (m - 1);
                    hj = base + __builtin_ctzll(m);
                }
                nc += take;
            }
        }

        // ---- penalty phase: lane = k*8 + t, t<6 live ----
        int k = lane >> 3;                               // pair index 0..7
        int t = lane & 7;                                // term index
        int hjk = __shfl(hj, k);
        float p = 0.0f;
        if (t < 6 && k < nc) {
            int d = (t >= 3) ? 1 : 0;                    // 0: recv field @ intr verts
            int v = t - 3 * d;
            int si = d ? hjk : i;                        // field source tri
            int qi = d ? i : hjk;                        // query tri
            int sa = faces[3 * si + 0], sb = faces[3 * si + 1], sc = faces[3 * si + 2];
            float s[9] = { verts[3 * sa + 0], verts[3 * sa + 1], verts[3 * sa + 2],
                           verts[3 * sb + 0], verts[3 * sb + 1], verts[3 * sb + 2],
                           verts[3 * sc + 0], verts[3 * sc + 1], verts[3 * sc + 2] };
            int qv = faces[3 * qi + v];
            p = cone_pen_v(s, verts[3 * qv + 0], verts[3 * qv + 1], verts[3 * qv + 2]);
        }
        acc += p;
    }

    // 64-lane butterfly, then block reduce, then ONE plain store per block.
#pragma unroll
    for (int off = 32; off > 0; off >>= 1) acc += __shfl_xor(acc, off);
    __shared__ float wsum[4];
    if (lane == 0) wsum[wid] = acc;
    __syncthreads();
    if (threadIdx.x == 0)
        partial[blockIdx.x] = wsum[0] + wsum[1] + wsum[2] + wsum[3];
}

// ---------------------------------------------------------------------------
// Sum the block partials into the scalar output (same order as always ->
// bit-identical result).
__global__ __launch_bounds__(256) void reduce_kernel(
    const float* __restrict__ partial, float* __restrict__ out)
{
    float a = 0.0f;
    for (int idx = threadIdx.x; idx < CBLK; idx += 256) a += partial[idx];
#pragma unroll
    for (int off = 32; off > 0; off >>= 1) a += __shfl_xor(a, off);
    __shared__ float ws[4];
    int lane = threadIdx.x & 63, wid = threadIdx.x >> 6;
    if (lane == 0) ws[wid] = a;
    __syncthreads();
    if (threadIdx.x == 0) out[0] = ws[0] + ws[1] + ws[2] + ws[3];
}

// ---------------------------------------------------------------------------
extern "C" void kernel_launch(void* const* d_in, const int* in_sizes, int n_in,
                              void* d_out, int out_size, void* d_ws, size_t ws_size,
                              hipStream_t stream) {
    const float* verts = (const float*)d_in[0];   // [1,NV,3] fp32
    const int*   faces = (const int*)d_in[1];     // [NF*3] int32
    float* out = (float*)d_out;                   // scalar fp32

    float* partial = (float*)d_ws;                // CBLK floats

    coll_kernel<<<CBLK, 256, 0, stream>>>(verts, faces, partial);
    reduce_kernel<<<1, 256, 0, stream>>>(partial, out);
}